// Round 12
// baseline (1818.131 us; speedup 1.0000x reference)
//
#include <hip/hip_runtime.h>

// HMM forward, B=64, T=1024, S=512, V=1024.
// TWO batches per block (grid 32), phase-interleaved: each barrier interval
// runs [quant phase of batch X] + [MFMA phase of batch Y] from the same
// waves, so the serial chain of one batch hides under the fp6 MFMA pipe of
// the other. E = exp(trans) fp6 e2m3 with per-(col,32-row-block) e8m0 scales,
// shared in registers between both batches. P fp6 with per-64-chunk scales.
// mfma_scale_f32_16x16x128_f8f6f4 (fp6 x fp6), all 16 A-rows identical ->
// every C row is the result. All layouts/numerics verbatim from r11
// (verified absmax 32 = bf16 output floor).

constexpr int Bn = 64, Tn = 1024, Sn = 512;
#define L2E 1.44269504f

typedef int v8i __attribute__((ext_vector_type(8)));
typedef float v4f __attribute__((ext_vector_type(4)));

template <int CTRL>
__device__ __forceinline__ int dpp_i(int x) {
    return __builtin_amdgcn_update_dpp(x, x, CTRL, 0xf, 0xf, false);
}
template <int CTRL>
__device__ __forceinline__ float dpp_fmax(float x) {
    int s = __builtin_bit_cast(int, x);
    int d = dpp_i<CTRL>(s);
    return fmaxf(x, __builtin_bit_cast(float, d));
}
__device__ __forceinline__ float wave_max64(float x) {
    x = dpp_fmax<0x121>(x);   // row_ror:1
    x = dpp_fmax<0x122>(x);   // row_ror:2
    x = dpp_fmax<0x124>(x);   // row_ror:4
    x = dpp_fmax<0x128>(x);   // row_ror:8
    x = dpp_fmax<0x142>(x);   // row_bcast:15
    x = dpp_fmax<0x143>(x);   // row_bcast:31
    return __builtin_bit_cast(float,
        __builtin_amdgcn_readlane(__builtin_bit_cast(int, x), 63));
}
__device__ __forceinline__ float max_of_8_pattern(float x) {
    x = dpp_fmax<0x121>(x);
    x = dpp_fmax<0x122>(x);
    x = dpp_fmax<0x124>(x);
    return x;
}
__device__ __forceinline__ int rl_i(int x, int l) {
    return __builtin_amdgcn_readlane(x, l);
}

// round-to-nearest e2m3 code (0..31) for v in [0, 7.5]
__device__ __forceinline__ int e2m3_rn(float v) {
    v = fminf(v, 7.5f);
    float mult = v < 2.f ? 8.f : (v < 4.f ? 4.f : 2.f);
    int   add  = v < 2.f ? 0   : (v < 4.f ? 8   : 16);
    return (int)rintf(v * mult) + add;
}

// ---- prep: quantize E to fp6 e2m3, dense 6-bit packed in MFMA-B lane fields
// (verbatim r11, verified). Thread handles (col j, 32-row block rb).
__global__ __launch_bounds__(64) void prep_E6(
    const float* __restrict__ trans, unsigned int* __restrict__ EqB6,
    unsigned char* __restrict__ SBtab)
{
    const int t = threadIdx.x;
    const int j = blockIdx.x * 4 + (t >> 4);
    const int rb = t & 15;

    float tv[32]; float tmax = -1e30f;
    #pragma unroll
    for (int k = 0; k < 32; ++k) {
        tv[k] = trans[(rb * 32 + k) * Sn + j];
        tmax = fmaxf(tmax, tv[k]);
    }
    float e = ceilf(fmaf(tmax, L2E, -2.9068906f));   // log2(7.5)

    unsigned dw[6] = {0, 0, 0, 0, 0, 0};
    #pragma unroll
    for (int k = 0; k < 32; ++k) {
        float v = exp2f(fmaf(tv[k], L2E, -e));
        unsigned c = (unsigned)e2m3_rn(v);
        int bit = 6 * k;
        dw[bit >> 5] |= c << (bit & 31);
        if ((bit & 31) > 26) dw[(bit >> 5) + 1] |= c >> (32 - (bit & 31));
    }

    int f = ((j >> 6) * 4 + ((j >> 4) & 3)) * 4 + (rb >> 2);
    int lane = (rb & 3) * 16 + (j & 15);
    unsigned base = (unsigned)(f * 64 + lane) * 6;
    #pragma unroll
    for (int d = 0; d < 6; ++d) EqB6[base + d] = dw[d];

    int sb = 127 + (int)e;
    SBtab[j * 16 + rb] = (unsigned char)(sb < 1 ? 1 : (sb > 254 ? 254 : sb));
}

__global__ __launch_bounds__(512, 2) void hmm_fwd(
    const int* __restrict__ obs,          // [B, T]
    const float* __restrict__ emis,       // [V, S]
    const float* __restrict__ prior,      // [S]
    const unsigned int* __restrict__ EqB6,// fp6 B lane fields, 6 dwords each
    const unsigned char* __restrict__ SBtab, // [512][16] e8m0 scale bytes
    float* __restrict__ out)              // [B]
{
    const int b2 = blockIdx.x * 2;        // batches b2 (A=0) and b2+1 (B=1)
    const int tid = threadIdx.x;          // state j owned by this thread
    const int lane = tid & 63, wv = tid >> 6;
    const int q = lane >> 4;              // 0..3
    const int hb = lane >> 5;             // 0..1

    __shared__ int obs_s[2][Tn];
    __shared__ __align__(16) unsigned int Pq6[2][96];  // per-batch packed P
    __shared__ float redm[2][8];
    __shared__ float reds[2][8];

    obs_s[0][tid] = obs[b2 * Tn + tid];
    obs_s[0][tid + 512] = obs[b2 * Tn + 512 + tid];
    obs_s[1][tid] = obs[(b2 + 1) * Tn + tid];
    obs_s[1][tid + 512] = obs[(b2 + 1) * Tn + 512 + tid];

    // E fragments (shared by both batches): Bf8[tau][kap], fp6-packed
    v8i Bf8[4][4];
    int SBv[4][4];
    #pragma unroll
    for (int tau = 0; tau < 4; ++tau) {
        int col = wv * 64 + tau * 16 + (lane & 15);
        #pragma unroll
        for (int kap = 0; kap < 4; ++kap) {
            const uint2* p = (const uint2*)(EqB6 +
                (unsigned)((((wv * 4 + tau) * 4 + kap) * 64 + lane) * 6));
            uint2 x0 = p[0], x1 = p[1], x2 = p[2];
            v8i bb = {(int)x0.x, (int)x0.y, (int)x1.x, (int)x1.y,
                      (int)x2.x, (int)x2.y, 0, 0};
            Bf8[tau][kap] = bb;
            SBv[tau][kap] = (int)SBtab[col * 16 + kap * 4 + q] * 0x01010101;
        }
    }

    __syncthreads();   // obs_s ready

    // ---- per-batch state (registers)
    float aA = emis[obs_s[0][0] * Sn + tid] + prior[tid];
    float aB = emis[obs_s[1][0] * Sn + tid] + prior[tid];
    float enA = emis[obs_s[0][1] * Sn + tid];
    float enB = emis[obs_s[1][1] * Sn + tid];
    float mwA, mwB, mAllA, mAllB;
    int sAA[4], sAB[4];

    // phase 1 (quantize + publish P) for batch X
    auto phase1 = [&](int X, float a, float mw, float& mAll, int* sA) {
        float r = redm[X][lane & 7];
        mAll = max_of_8_pattern(r);
        float nf = fmaxf(floorf((r - mAll) * L2E), -110.f);
        int sb = 126 + (int)nf;
        int sbdup = sb * 0x01010101;
        float nown = fmaxf(floorf((mw - mAll) * L2E), -110.f);
        float v = exp2f(fmaf(a - mAll, L2E, 1.0f - nown));
        int code = e2m3_rn(v);
        int p1 = dpp_i<0xB1>(code);               // quad_perm [1,0,3,2]
        int m1 = (lane & 1) ? (p1 | (code << 6)) : (code | (p1 << 6));
        int p2 = dpp_i<0x4E>(m1);                 // quad_perm [2,3,0,1]
        int w24 = (lane & 2) ? (p2 | (m1 << 12)) : (m1 | (p2 << 12));
        int rowbase = lane & 48;
        int w1 = __shfl(w24, rowbase + 4, 64);
        int w2 = __shfl(w24, rowbase + 8, 64);
        int w3 = __shfl(w24, rowbase + 12, 64);
        int sel = lane & 15;
        unsigned dwv = sel == 0 ? (unsigned)(w24 | (w1 << 24))
                     : sel == 1 ? (unsigned)(((unsigned)w1 >> 8) | (w2 << 16))
                                : (unsigned)(((unsigned)w2 >> 16) | (w3 << 8));
        if (sel < 3) Pq6[X][3 * (tid >> 4) + sel] = dwv;
        int ee0 = rl_i(sbdup, 0), ee1 = rl_i(sbdup, 1);
        int ee2 = rl_i(sbdup, 2), ee3 = rl_i(sbdup, 3);
        int ee4 = rl_i(sbdup, 4), ee5 = rl_i(sbdup, 5);
        int ee6 = rl_i(sbdup, 6), ee7 = rl_i(sbdup, 7);
        sA[0] = hb ? ee1 : ee0;
        sA[1] = hb ? ee3 : ee2;
        sA[2] = hb ? ee5 : ee4;
        sA[3] = hb ? ee7 : ee6;
    };

    // phase 2 head: A-frag reads + 16 scale-MFMAs for batch Y
    auto p2head = [&](int Y, const int* sA, float* accx) {
        v8i Af8[4];
        #pragma unroll
        for (int kap = 0; kap < 4; ++kap) {
            const uint2* pp = (const uint2*)(Pq6[Y] + kap * 24 + q * 6);
            uint2 x0 = pp[0], x1 = pp[1], x2 = pp[2];
            v8i aa = {(int)x0.x, (int)x0.y, (int)x1.x, (int)x1.y,
                      (int)x2.x, (int)x2.y, 0, 0};
            Af8[kap] = aa;
        }
        #pragma unroll
        for (int tau = 0; tau < 4; ++tau) {
            v4f z = {0.f, 0.f, 0.f, 0.f};
            #pragma unroll
            for (int kap = 0; kap < 4; ++kap)
                z = __builtin_amdgcn_mfma_scale_f32_16x16x128_f8f6f4(
                        Af8[kap], Bf8[tau][kap], z, 2, 2,
                        0, sA[kap], 0, SBv[tau][kap]);
            accx[tau] = z.x;
        }
    };

    // phase 2 tail: result select, alpha update, wave max, redm publish
    auto p2tail = [&](int Y, const float* accx, float& a, float& en,
                      float mAll, float& mw, int t) {
        float fs = (lane < 16) ? accx[0]
                 : (lane < 32) ? accx[1]
                 : (lane < 48) ? accx[2]
                               : accx[3];
        float e_cur = en;
        int tn = (t + 1 < Tn) ? t + 1 : Tn - 1;
        en = emis[obs_s[Y][tn] * Sn + tid];
        a = e_cur + mAll + __logf(fs);
        mw = wave_max64(a);
        if (lane == 0) redm[Y][wv] = mw;
    };

    // ---- prologue: publish initial wave maxes; bring B a half-step ahead
    mwA = wave_max64(aA);
    mwB = wave_max64(aB);
    if (lane == 0) { redm[0][wv] = mwA; redm[1][wv] = mwB; }
    __syncthreads();
    phase1(1, aB, mwB, mAllB, sAB);       // quantize B for step 1
    __syncthreads();

    // ---- main loop: 2 intervals per t; one batch-step of each per iteration
    for (int t = 1; t < Tn; ++t) {
        // interval alpha: MFMA-B(t) + quant-A(t)
        float axB[4];
        p2head(1, sAB, axB);
        phase1(0, aA, mwA, mAllA, sAA);
        p2tail(1, axB, aB, enB, mAllB, mwB, t);
        __syncthreads();

        // interval beta: MFMA-A(t) + quant-B(t+1)
        float axA[4];
        p2head(0, sAA, axA);
        phase1(1, aB, mwB, mAllB, sAB);   // harmless extra run at t=Tn-1
        p2tail(0, axA, aA, enA, mAllA, mwA, t);
        __syncthreads();
    }

    // ---- epilogue: out[b] = logsumexp_j(alpha[j]) for both batches
    float mA = wave_max64(aA);
    float mB = wave_max64(aB);
    if (lane == 0) { redm[0][wv] = mA; redm[1][wv] = mB; }
    __syncthreads();
    float MA = redm[0][0], MB = redm[1][0];
    #pragma unroll
    for (int w = 1; w < 8; ++w) {
        MA = fmaxf(MA, redm[0][w]);
        MB = fmaxf(MB, redm[1][w]);
    }
    float sA_ = __expf(aA - MA);
    float sB_ = __expf(aB - MB);
    #pragma unroll
    for (int off = 32; off; off >>= 1) {
        sA_ += __shfl_xor(sA_, off, 64);
        sB_ += __shfl_xor(sB_, off, 64);
    }
    if (lane == 0) { reds[0][wv] = sA_; reds[1][wv] = sB_; }
    __syncthreads();
    if (tid == 0) {
        float t0 = 0.f, t1 = 0.f;
        #pragma unroll
        for (int w = 0; w < 8; ++w) { t0 += reds[0][w]; t1 += reds[1][w]; }
        out[b2] = MA + __logf(t0);
        out[b2 + 1] = MB + __logf(t1);
    }
}

extern "C" void kernel_launch(void* const* d_in, const int* in_sizes, int n_in,
                              void* d_out, int out_size, void* d_ws, size_t ws_size,
                              hipStream_t stream) {
    const int*   obs   = (const int*)d_in[0];
    const float* emis  = (const float*)d_in[1];
    const float* trans = (const float*)d_in[2];
    const float* prior = (const float*)d_in[3];
    float* out = (float*)d_out;

    unsigned int* EqB6 = (unsigned int*)d_ws;                      // 192 KB
    unsigned char* SBtab = (unsigned char*)d_ws + Sn * Sn * 6 / 8; // 8 KB

    prep_E6<<<Sn / 4, 64, 0, stream>>>(trans, EqB6, SBtab);
    hmm_fwd<<<Bn / 2, Sn, 0, stream>>>(obs, emis, prior, EqB6, SBtab, out);
}